// Round 4
// baseline (1801.622 us; speedup 1.0000x reference)
//
#include <hip/hip_runtime.h>
#include <math.h>

#define N_NODES 100000
#define N_EDGES 1600000
#define EN_TOT  (N_EDGES + N_NODES)
#define BATCH   16
#define EDGE_DIM 16
#define NEG_SLOPE 0.2f
#define NB_SCAN 391   // ceil(N_NODES/256)

__device__ __forceinline__ int rfl(int v) { return __builtin_amdgcn_readfirstlane(v); }

// ---------------- utility ----------------
__global__ void zero_kernel(float* __restrict__ p, long long n) {
    long long i = (long long)blockIdx.x * blockDim.x + threadIdx.x;
    long long stride = (long long)gridDim.x * blockDim.x;
    for (; i < n; i += stride) p[i] = 0.0f;
}

// ---------------- CSR build ----------------
__global__ void count_deg(const int* __restrict__ dst, int* __restrict__ deg) {
    int e = blockIdx.x * 256 + threadIdx.x;
    if (e < N_EDGES) atomicAdd(&deg[dst[e]], 1);
}

__global__ __launch_bounds__(256) void scan1(const int* __restrict__ deg,
                                             int* __restrict__ incl, int* __restrict__ bsum) {
    __shared__ int s[256];
    int n = blockIdx.x * 256 + threadIdx.x;
    int v = (n < N_NODES) ? deg[n] + 1 : 0;
    s[threadIdx.x] = v;
    __syncthreads();
    for (int off = 1; off < 256; off <<= 1) {
        int t = (threadIdx.x >= off) ? s[threadIdx.x - off] : 0;
        __syncthreads();
        s[threadIdx.x] += t;
        __syncthreads();
    }
    if (n < N_NODES) incl[n] = s[threadIdx.x];
    if (threadIdx.x == 255) bsum[blockIdx.x] = s[255];
}

__global__ __launch_bounds__(512) void scan2(int* __restrict__ bsum) {
    __shared__ int s[512];
    int t = threadIdx.x;
    int v = (t < NB_SCAN) ? bsum[t] : 0;
    s[t] = v;
    __syncthreads();
    for (int off = 1; off < 512; off <<= 1) {
        int u = (t >= off) ? s[t - off] : 0;
        __syncthreads();
        s[t] += u;
        __syncthreads();
    }
    if (t < NB_SCAN) bsum[t] = s[t] - v;  // exclusive block prefix
}

__global__ void scan3(const int* __restrict__ incl, const int* __restrict__ deg,
                      const int* __restrict__ bsum, int* __restrict__ offs) {
    int n = blockIdx.x * 256 + threadIdx.x;
    if (n < N_NODES) offs[n] = incl[n] - (deg[n] + 1) + bsum[blockIdx.x];
    if (n == 0) offs[N_NODES] = EN_TOT;
}

__global__ void scatter(const int* __restrict__ src, const int* __restrict__ dst,
                        const int* __restrict__ offs, int* __restrict__ cursor,
                        int* __restrict__ csr_src, int* __restrict__ csr_eid) {
    int e = blockIdx.x * 256 + threadIdx.x;
    if (e < N_EDGES) {
        int d = dst[e];
        int r = atomicAdd(&cursor[d], 1);
        int pos = offs[d] + r;
        csr_src[pos] = src[e];
        csr_eid[pos] = e;
    } else if (e < EN_TOT) {
        int n = e - N_EDGES;
        int pos = offs[n + 1] - 1;
        csr_src[pos] = n;
        csr_eid[pos] = N_EDGES + n;  // marker: self-loop
    }
}

__global__ __launch_bounds__(256) void loopattr_csr(const int* __restrict__ offs,
                                                    const int* __restrict__ csr_eid,
                                                    const float* __restrict__ ea,
                                                    float* __restrict__ lattr) {
    int node = blockIdx.x * 4 + (threadIdx.x >> 6);
    if (node >= N_NODES) return;
    int lane = threadIdx.x & 63;
    int row = offs[node];
    int degn = offs[node + 1] - 1 - row;  // real edges only
    int k = lane & 15, grp = lane >> 4;
    float acc = 0.0f;
    for (int i = grp; i < degn; i += 4) {
        int eid = csr_eid[row + i];
        acc += ea[(long long)eid * EDGE_DIM + k];
    }
    acc += __shfl_xor(acc, 16);
    acc += __shfl_xor(acc, 32);
    if (lane < 16) lattr[(long long)node * EDGE_DIM + k] = acc / fmaxf((float)degn, 1.0f);
}

// ---------------- dense transforms (register-tiled, LDS broadcast reads) ----------------
// Block: 256 thr, 32 rows. Wave w -> rows w*8..w*8+7. Each thread: 4 output cols
// {Wl[lane], Wl[lane+64], Wr[lane], Wr[lane+64]} x 8 rows. srow reads are wave-uniform
// addresses -> LDS broadcast (conflict-free, ~free); VALU-bound at f32 FMA rate.
template<int K>
__global__ __launch_bounds__(256) void dual_linear(
    const float* __restrict__ in,
    const float* __restrict__ Wl, const float* __restrict__ bl,
    const float* __restrict__ Wr, const float* __restrict__ br,
    float* __restrict__ outl, float* __restrict__ outr, int N)
{
    constexpr int ROWS = 32;
    constexpr int K4 = K / 4;
    __shared__ float4 srow[ROWS][K4];
    int t = threadIdx.x;
    int base = blockIdx.x * ROWS;
    {
        const float4* in4 = (const float4*)in;
        for (int idx = t; idx < ROWS * K4; idx += 256) {
            int r = idx / K4, kk = idx - r * K4;
            int n = base + r;
            srow[r][kk] = (n < N) ? in4[(size_t)n * K4 + kk] : make_float4(0.f, 0.f, 0.f, 0.f);
        }
    }
    __syncthreads();
    int lane = t & 63;
    int r0 = (t >> 6) * 8;
    const float4* Wl4 = (const float4*)Wl;
    const float4* Wr4 = (const float4*)Wr;
    float acc[4][8];
    float b0 = bl[lane], b1 = bl[lane + 64], b2 = br[lane], b3 = br[lane + 64];
#pragma unroll
    for (int rr = 0; rr < 8; ++rr) {
        acc[0][rr] = b0; acc[1][rr] = b1; acc[2][rr] = b2; acc[3][rr] = b3;
    }
    for (int kk = 0; kk < K4; ++kk) {
        float4 w0 = Wl4[(size_t)lane * K4 + kk];
        float4 w1 = Wl4[(size_t)(lane + 64) * K4 + kk];
        float4 w2 = Wr4[(size_t)lane * K4 + kk];
        float4 w3 = Wr4[(size_t)(lane + 64) * K4 + kk];
#pragma unroll
        for (int rr = 0; rr < 8; ++rr) {
            float4 a = srow[r0 + rr][kk];   // wave-uniform -> broadcast
            acc[0][rr] = fmaf(a.x, w0.x, acc[0][rr]); acc[0][rr] = fmaf(a.y, w0.y, acc[0][rr]);
            acc[0][rr] = fmaf(a.z, w0.z, acc[0][rr]); acc[0][rr] = fmaf(a.w, w0.w, acc[0][rr]);
            acc[1][rr] = fmaf(a.x, w1.x, acc[1][rr]); acc[1][rr] = fmaf(a.y, w1.y, acc[1][rr]);
            acc[1][rr] = fmaf(a.z, w1.z, acc[1][rr]); acc[1][rr] = fmaf(a.w, w1.w, acc[1][rr]);
            acc[2][rr] = fmaf(a.x, w2.x, acc[2][rr]); acc[2][rr] = fmaf(a.y, w2.y, acc[2][rr]);
            acc[2][rr] = fmaf(a.z, w2.z, acc[2][rr]); acc[2][rr] = fmaf(a.w, w2.w, acc[2][rr]);
            acc[3][rr] = fmaf(a.x, w3.x, acc[3][rr]); acc[3][rr] = fmaf(a.y, w3.y, acc[3][rr]);
            acc[3][rr] = fmaf(a.z, w3.z, acc[3][rr]); acc[3][rr] = fmaf(a.w, w3.w, acc[3][rr]);
        }
    }
#pragma unroll
    for (int rr = 0; rr < 8; ++rr) {
        int n = base + r0 + rr;
        if (n < N) {
            outl[(size_t)n * 128 + lane]      = acc[0][rr];
            outl[(size_t)n * 128 + lane + 64] = acc[1][rr];
            outr[(size_t)n * 128 + lane]      = acc[2][rr];
            outr[(size_t)n * 128 + lane + 64] = acc[3][rr];
        }
    }
}

// ---------------- fused GATv2 ----------------
// one wave per node; lane owns channels c0=lane, c1=lane+64.
// attr: wave-uniform address (readfirstlane) -> 4x float4 broadcast loads (no shfl).
// softmax: defer-max (THR=8). 1-deep software pipeline on attr + xl gathers.
template<int DO_ELU>
__global__ __launch_bounds__(256) void gat_fused(
    const int* __restrict__ offs, const int* __restrict__ csr_src,
    const int* __restrict__ csr_eid,
    const float* __restrict__ ea, const float* __restrict__ lattr,
    const float* __restrict__ We, const float* __restrict__ att,
    const float* __restrict__ xl, const float* __restrict__ xr,
    const float* __restrict__ bias, float* __restrict__ y)
{
    int node = blockIdx.x * 4 + (threadIdx.x >> 6);
    if (node >= N_NODES) return;
    int lane = threadIdx.x & 63;
    int c0 = lane, c1 = lane + 64;

    const float4* We4 = (const float4*)We;
    float4 we0[4], we1[4];
#pragma unroll
    for (int q = 0; q < 4; ++q) {
        we0[q] = We4[c0 * 4 + q];
        we1[q] = We4[c1 * 4 + q];
    }
    float att0 = att[c0], att1 = att[c1];

    int row = offs[node], rend = offs[node + 1];
    float xr0 = xr[(size_t)node * 128 + c0];
    float xr1 = xr[(size_t)node * 128 + c1];

    float m0 = -INFINITY, m1 = -INFINITY;
    float d0 = 0.0f, d1 = 0.0f, acc0 = 0.0f, acc1 = 0.0f;

    // prologue: load edge `row`
    int sC = rfl(csr_src[row]);
    int eC = rfl(csr_eid[row]);
    const float4* apC = (const float4*)((eC < N_EDGES) ? ea + (size_t)eC * EDGE_DIM
                                                       : lattr + (size_t)(eC - N_EDGES) * EDGE_DIM);
    float4 A0 = apC[0], A1 = apC[1], A2 = apC[2], A3 = apC[3];
    float xls0 = xl[(size_t)sC * 128 + c0];
    float xls1 = xl[(size_t)sC * 128 + c1];

    for (int i = row; i < rend; ++i) {
        // prefetch edge i+1 (wave-uniform condition)
        bool have = (i + 1 < rend);
        float4 nA0, nA1, nA2, nA3;
        float nx0, nx1;
        if (have) {
            int sN = rfl(csr_src[i + 1]);
            int eN = rfl(csr_eid[i + 1]);
            const float4* apN = (const float4*)((eN < N_EDGES) ? ea + (size_t)eN * EDGE_DIM
                                                               : lattr + (size_t)(eN - N_EDGES) * EDGE_DIM);
            nA0 = apN[0]; nA1 = apN[1]; nA2 = apN[2]; nA3 = apN[3];
            nx0 = xl[(size_t)sN * 128 + c0];
            nx1 = xl[(size_t)sN * 128 + c1];
        }

        // ---- compute current edge ----
        float e0 = 0.0f, e1 = 0.0f;
        {
            float4 a;
            a = A0;
            e0 = fmaf(a.x, we0[0].x, e0); e0 = fmaf(a.y, we0[0].y, e0);
            e0 = fmaf(a.z, we0[0].z, e0); e0 = fmaf(a.w, we0[0].w, e0);
            e1 = fmaf(a.x, we1[0].x, e1); e1 = fmaf(a.y, we1[0].y, e1);
            e1 = fmaf(a.z, we1[0].z, e1); e1 = fmaf(a.w, we1[0].w, e1);
            a = A1;
            e0 = fmaf(a.x, we0[1].x, e0); e0 = fmaf(a.y, we0[1].y, e0);
            e0 = fmaf(a.z, we0[1].z, e0); e0 = fmaf(a.w, we0[1].w, e0);
            e1 = fmaf(a.x, we1[1].x, e1); e1 = fmaf(a.y, we1[1].y, e1);
            e1 = fmaf(a.z, we1[1].z, e1); e1 = fmaf(a.w, we1[1].w, e1);
            a = A2;
            e0 = fmaf(a.x, we0[2].x, e0); e0 = fmaf(a.y, we0[2].y, e0);
            e0 = fmaf(a.z, we0[2].z, e0); e0 = fmaf(a.w, we0[2].w, e0);
            e1 = fmaf(a.x, we1[2].x, e1); e1 = fmaf(a.y, we1[2].y, e1);
            e1 = fmaf(a.z, we1[2].z, e1); e1 = fmaf(a.w, we1[2].w, e1);
            a = A3;
            e0 = fmaf(a.x, we0[3].x, e0); e0 = fmaf(a.y, we0[3].y, e0);
            e0 = fmaf(a.z, we0[3].z, e0); e0 = fmaf(a.w, we0[3].w, e0);
            e1 = fmaf(a.x, we1[3].x, e1); e1 = fmaf(a.y, we1[3].y, e1);
            e1 = fmaf(a.z, we1[3].z, e1); e1 = fmaf(a.w, we1[3].w, e1);
        }
        float v0 = xls0 + xr0 + e0, v1 = xls1 + xr1 + e1;
        v0 = (v0 > 0.0f) ? v0 : NEG_SLOPE * v0;
        v1 = (v1 > 0.0f) ? v1 : NEG_SLOPE * v1;
        float p0 = v0 * att0, p1 = v1 * att1;
#pragma unroll
        for (int off = 1; off <= 16; off <<= 1) {
            p0 += __shfl_xor(p0, off);
            p1 += __shfl_xor(p1, off);
        }
        // defer-max online softmax (THR=8): rescale only when max rises >8
        if (p0 - m0 > 8.0f) { float r = __expf(m0 - p0); d0 *= r; acc0 *= r; m0 = p0; }
        float w0 = __expf(p0 - m0); d0 += w0; acc0 += w0 * xls0;
        if (p1 - m1 > 8.0f) { float r = __expf(m1 - p1); d1 *= r; acc1 *= r; m1 = p1; }
        float w1 = __expf(p1 - m1); d1 += w1; acc1 += w1 * xls1;

        // rotate
        if (have) {
            A0 = nA0; A1 = nA1; A2 = nA2; A3 = nA3;
            xls0 = nx0; xls1 = nx1;
        }
    }

    float o0 = acc0 / d0 + bias[c0];
    float o1 = acc1 / d1 + bias[c1];
    if (DO_ELU) {
        o0 = (o0 > 0.0f) ? o0 : (__expf(o0) - 1.0f);
        o1 = (o1 > 0.0f) ? o1 : (__expf(o1) - 1.0f);
    }
    y[(size_t)node * 128 + c0] = o0;
    y[(size_t)node * 128 + c1] = o1;
}

// ---------------- pool (segmented reduction over sorted batch) + head ----------------
__global__ __launch_bounds__(256) void pool_csr(const float* __restrict__ y,
                                                const int* __restrict__ batch,
                                                float* __restrict__ gsum,
                                                float* __restrict__ gcnt) {
    int base = blockIdx.x * 256;
    int t = threadIdx.x;
    int c = t & 127, h = t >> 7;
    int n = base + h;
    int end = min(base + 256, N_NODES);
    if (n >= end) return;
    float acc = 0.0f, cnt = 0.0f;
    int curb = batch[n];
    for (; n < end; n += 2) {
        int b = batch[n];
        if (b != curb) {
            atomicAdd(&gsum[curb * 128 + c], acc);
            if (c == 0) atomicAdd(&gcnt[curb], cnt);
            acc = 0.0f; cnt = 0.0f; curb = b;
        }
        acc += y[(long long)n * 128 + c];
        cnt += 1.0f;
    }
    atomicAdd(&gsum[curb * 128 + c], acc);
    if (c == 0) atomicAdd(&gcnt[curb], cnt);
}

__global__ __launch_bounds__(128) void head_kernel(
    const float* __restrict__ gsum, const float* __restrict__ gcnt,
    const float* __restrict__ Wg1, const float* __restrict__ bg1,
    const float* __restrict__ Wg2, const float* __restrict__ bg2,
    const float* __restrict__ Wp, const float* __restrict__ bp,
    float* __restrict__ out)
{
    int b = blockIdx.x;
    int j = threadIdx.x;
    __shared__ float g[128], h[128];
    float cntv = fmaxf(gcnt[b], 1.0f);
    g[j] = gsum[b * 128 + j] / cntv;
    __syncthreads();
    float a = bg1[j];
    for (int k = 0; k < 128; ++k) a += g[k] * Wg1[j * 128 + k];
    h[j] = fmaxf(a, 0.0f);
    __syncthreads();
    if (j < 15) {
        float o = bg2[j];
        for (int k = 0; k < 128; ++k) o += h[k] * Wg2[j * 128 + k];
        out[b * 25 + j] = o;
    }
    if (j >= 64 && j < 74) {
        int p = j - 64;
        float o = bp[p];
        for (int k = 0; k < 128; ++k) o += g[k] * Wp[p * 128 + k];
        out[b * 25 + 15 + p] = o;
    }
}

// ---------------- launch ----------------
extern "C" void kernel_launch(void* const* d_in, const int* in_sizes, int n_in,
                              void* d_out, int out_size, void* d_ws, size_t ws_size,
                              hipStream_t stream)
{
    const float* x     = (const float*)d_in[0];
    const int*   ei    = (const int*)  d_in[1];
    const float* ea    = (const float*)d_in[2];
    const int*   batch = (const int*)  d_in[3];
    const float* W1l = (const float*)d_in[4],  *b1l  = (const float*)d_in[5];
    const float* W1r = (const float*)d_in[6],  *b1r  = (const float*)d_in[7];
    const float* W1e = (const float*)d_in[8],  *att1 = (const float*)d_in[9];
    const float* bias1 = (const float*)d_in[10];
    const float* W2l = (const float*)d_in[11], *b2l  = (const float*)d_in[12];
    const float* W2r = (const float*)d_in[13], *b2r  = (const float*)d_in[14];
    const float* W2e = (const float*)d_in[15], *att2 = (const float*)d_in[16];
    const float* bias2 = (const float*)d_in[17];
    const float* Wg1 = (const float*)d_in[18], *bg1 = (const float*)d_in[19];
    const float* Wg2 = (const float*)d_in[20], *bg2 = (const float*)d_in[21];
    const float* Wp  = (const float*)d_in[22], *bp  = (const float*)d_in[23];
    const int* src = ei;
    const int* dst = ei + N_EDGES;

    // workspace layout (float units)
    float* ws = (float*)d_ws;
    size_t o = 0;
    float* xl    = ws + o; o += (size_t)N_NODES * 128;
    float* xr    = ws + o; o += (size_t)N_NODES * 128;
    float* y     = ws + o; o += (size_t)N_NODES * 128;
    float* lattr = ws + o; o += (size_t)N_NODES * EDGE_DIM;
    int* csr_src = (int*)(ws + o); o += (size_t)EN_TOT;
    int* csr_eid = (int*)(ws + o); o += (size_t)EN_TOT;
    int* offs    = (int*)(ws + o); o += (size_t)N_NODES + 1;
    int* deg     = (int*)(ws + o); o += (size_t)N_NODES;          // start of zero region
    int* cursor  = (int*)(ws + o); o += (size_t)N_NODES;
    float* gsum  = ws + o; o += (size_t)BATCH * 128;
    float* gcnt  = ws + o; o += (size_t)BATCH;                     // end of zero region
    int* bsum    = (int*)(ws + o); o += 512;
    int* incl    = (int*)y;  // scan temp, dead before y is written

    float* out = (float*)d_out;

    // zero deg, cursor, gsum, gcnt (contiguous)
    long long nz = (long long)N_NODES * 2 + BATCH * 128 + BATCH;
    zero_kernel<<<512, 256, 0, stream>>>((float*)deg, nz);

    // ---- CSR build (shared by both layers) ----
    count_deg<<<(N_EDGES + 255) / 256, 256, 0, stream>>>(dst, deg);
    scan1<<<NB_SCAN, 256, 0, stream>>>(deg, incl, bsum);
    scan2<<<1, 512, 0, stream>>>(bsum);
    scan3<<<NB_SCAN, 256, 0, stream>>>(incl, deg, bsum, offs);
    scatter<<<(EN_TOT + 255) / 256, 256, 0, stream>>>(src, dst, offs, cursor, csr_src, csr_eid);
    loopattr_csr<<<(N_NODES + 3) / 4, 256, 0, stream>>>(offs, csr_eid, ea, lattr);

    const int GAT_BLK = (N_NODES + 3) / 4;

    // ---- layer 1 ----
    dual_linear<32><<<(N_NODES + 31) / 32, 256, 0, stream>>>(x, W1l, b1l, W1r, b1r, xl, xr, N_NODES);
    gat_fused<1><<<GAT_BLK, 256, 0, stream>>>(offs, csr_src, csr_eid, ea, lattr,
                                              W1e, att1, xl, xr, bias1, y);

    // ---- layer 2 ----
    dual_linear<128><<<(N_NODES + 31) / 32, 256, 0, stream>>>(y, W2l, b2l, W2r, b2r, xl, xr, N_NODES);
    gat_fused<0><<<GAT_BLK, 256, 0, stream>>>(offs, csr_src, csr_eid, ea, lattr,
                                              W2e, att2, xl, xr, bias2, y);

    // ---- pool + head ----
    pool_csr<<<(N_NODES + 255) / 256, 256, 0, stream>>>(y, batch, gsum, gcnt);
    head_kernel<<<BATCH, 128, 0, stream>>>(gsum, gcnt, Wg1, bg1, Wg2, bg2, Wp, bp, out);
}

// Round 5
// 1079.718 us; speedup vs baseline: 1.6686x; 1.6686x over previous
//
#include <hip/hip_runtime.h>
#include <math.h>

#define N_NODES 100000
#define N_EDGES 1600000
#define EN_TOT  (N_EDGES + N_NODES)
#define BATCH   16
#define EDGE_DIM 16
#define NEG_SLOPE 0.2f
#define NB_SCAN 391   // ceil(N_NODES/256)

__device__ __forceinline__ int rfl(int v) { return __builtin_amdgcn_readfirstlane(v); }

// reduce-add over each 32-lane group via ds_swizzle (xor butterfly, zero addr VALU)
__device__ __forceinline__ float red32(float p) {
    p += __int_as_float(__builtin_amdgcn_ds_swizzle(__float_as_int(p), 0x041F));
    p += __int_as_float(__builtin_amdgcn_ds_swizzle(__float_as_int(p), 0x081F));
    p += __int_as_float(__builtin_amdgcn_ds_swizzle(__float_as_int(p), 0x101F));
    p += __int_as_float(__builtin_amdgcn_ds_swizzle(__float_as_int(p), 0x201F));
    p += __int_as_float(__builtin_amdgcn_ds_swizzle(__float_as_int(p), 0x401F));
    return p;
}

// ---------------- utility ----------------
__global__ void zero_kernel(float* __restrict__ p, long long n) {
    long long i = (long long)blockIdx.x * blockDim.x + threadIdx.x;
    long long stride = (long long)gridDim.x * blockDim.x;
    for (; i < n; i += stride) p[i] = 0.0f;
}

// ---------------- CSR build ----------------
__global__ void count_deg(const int* __restrict__ dst, int* __restrict__ deg) {
    int e = blockIdx.x * 256 + threadIdx.x;
    if (e < N_EDGES) atomicAdd(&deg[dst[e]], 1);
}

__global__ __launch_bounds__(256) void scan1(const int* __restrict__ deg,
                                             int* __restrict__ incl, int* __restrict__ bsum) {
    __shared__ int s[256];
    int n = blockIdx.x * 256 + threadIdx.x;
    int v = (n < N_NODES) ? deg[n] + 1 : 0;
    s[threadIdx.x] = v;
    __syncthreads();
    for (int off = 1; off < 256; off <<= 1) {
        int t = (threadIdx.x >= off) ? s[threadIdx.x - off] : 0;
        __syncthreads();
        s[threadIdx.x] += t;
        __syncthreads();
    }
    if (n < N_NODES) incl[n] = s[threadIdx.x];
    if (threadIdx.x == 255) bsum[blockIdx.x] = s[255];
}

__global__ __launch_bounds__(512) void scan2(int* __restrict__ bsum) {
    __shared__ int s[512];
    int t = threadIdx.x;
    int v = (t < NB_SCAN) ? bsum[t] : 0;
    s[t] = v;
    __syncthreads();
    for (int off = 1; off < 512; off <<= 1) {
        int u = (t >= off) ? s[t - off] : 0;
        __syncthreads();
        s[t] += u;
        __syncthreads();
    }
    if (t < NB_SCAN) bsum[t] = s[t] - v;  // exclusive block prefix
}

__global__ void scan3(const int* __restrict__ incl, const int* __restrict__ deg,
                      const int* __restrict__ bsum, int* __restrict__ offs) {
    int n = blockIdx.x * 256 + threadIdx.x;
    if (n < N_NODES) offs[n] = incl[n] - (deg[n] + 1) + bsum[blockIdx.x];
    if (n == 0) offs[N_NODES] = EN_TOT;
}

__global__ void scatter(const int* __restrict__ src, const int* __restrict__ dst,
                        const int* __restrict__ offs, int* __restrict__ cursor,
                        int* __restrict__ csr_src, int* __restrict__ csr_eid) {
    int e = blockIdx.x * 256 + threadIdx.x;
    if (e < N_EDGES) {
        int d = dst[e];
        int r = atomicAdd(&cursor[d], 1);
        int pos = offs[d] + r;
        csr_src[pos] = src[e];
        csr_eid[pos] = e;
    } else if (e < EN_TOT) {
        int n = e - N_EDGES;
        int pos = offs[n + 1] - 1;
        csr_src[pos] = n;
        csr_eid[pos] = N_EDGES + n;  // marker: self-loop
    }
}

__global__ __launch_bounds__(256) void loopattr_csr(const int* __restrict__ offs,
                                                    const int* __restrict__ csr_eid,
                                                    const float* __restrict__ ea,
                                                    float* __restrict__ lattr) {
    int node = blockIdx.x * 4 + (threadIdx.x >> 6);
    if (node >= N_NODES) return;
    int lane = threadIdx.x & 63;
    int row = offs[node];
    int degn = offs[node + 1] - 1 - row;  // real edges only
    int k = lane & 15, grp = lane >> 4;
    float acc = 0.0f;
    for (int i = grp; i < degn; i += 4) {
        int eid = csr_eid[row + i];
        acc += ea[(long long)eid * EDGE_DIM + k];
    }
    acc += __shfl_xor(acc, 16);
    acc += __shfl_xor(acc, 32);
    if (lane < 16) lattr[(long long)node * EDGE_DIM + k] = acc / fmaxf((float)degn, 1.0f);
}

// ---------------- dense transforms (R3 version — block-uniform LDS broadcast) ----------------
template<int K>
__global__ __launch_bounds__(256) void dual_linear(
    const float* __restrict__ in,
    const float* __restrict__ Wl, const float* __restrict__ bl,
    const float* __restrict__ Wr, const float* __restrict__ br,
    float* __restrict__ outl, float* __restrict__ outr, int N)
{
    constexpr int ROWS = 32;
    __shared__ float srow[ROWS][K];
    int t = threadIdx.x;
    int base = blockIdx.x * ROWS;
    for (int i = t; i < ROWS * K; i += 256) {
        int r = i / K, k = i - r * K;
        int n = base + r;
        srow[r][k] = (n < N) ? in[(long long)n * K + k] : 0.0f;
    }
    __syncthreads();
    const float* W  = (t < 128) ? Wl : Wr;
    const float* bb = (t < 128) ? bl : br;
    float* outp     = (t < 128) ? outl : outr;
    int j = t & 127;
    float bj = bb[j];
    float acc[ROWS];
#pragma unroll
    for (int r = 0; r < ROWS; ++r) acc[r] = bj;
    for (int k = 0; k < K; ++k) {
        float w = W[j * K + k];
#pragma unroll
        for (int r = 0; r < ROWS; ++r) acc[r] += srow[r][k] * w;
    }
    for (int r = 0; r < ROWS; ++r) {
        int n = base + r;
        if (n < N) outp[(long long)n * 128 + j] = acc[r];
    }
}

// ---------------- fused GATv2 ----------------
// one wave per node; lane owns channels c0=lane, c1=lane+64.
// Loop bounds readfirstlane'd -> csr/attr addresses wave-uniform -> scalar (SMEM) loads.
// ds_swizzle butterfly reduce; defer-max softmax (THR=8); 1-deep prefetch of xl gathers.
template<int DO_ELU>
__global__ __launch_bounds__(256) void gat_fused(
    const int* __restrict__ offs, const int* __restrict__ csr_src,
    const int* __restrict__ csr_eid,
    const float* __restrict__ ea, const float* __restrict__ lattr,
    const float* __restrict__ We, const float* __restrict__ att,
    const float* __restrict__ xl, const float* __restrict__ xr,
    const float* __restrict__ bias, float* __restrict__ y)
{
    int node = blockIdx.x * 4 + (threadIdx.x >> 6);
    if (node >= N_NODES) return;
    int lane = threadIdx.x & 63;
    int c0 = lane, c1 = lane + 64;

    float we0[EDGE_DIM], we1[EDGE_DIM];
#pragma unroll
    for (int k = 0; k < EDGE_DIM; ++k) {
        we0[k] = We[c0 * EDGE_DIM + k];
        we1[k] = We[c1 * EDGE_DIM + k];
    }
    float att0 = att[c0], att1 = att[c1];

    int row  = rfl(offs[node]);
    int rend = rfl(offs[node + 1]);
    float xr0 = xr[(size_t)node * 128 + c0];
    float xr1 = xr[(size_t)node * 128 + c1];

    float m0 = -INFINITY, m1 = -INFINITY;
    float d0 = 0.0f, d1 = 0.0f, acc0 = 0.0f, acc1 = 0.0f;

    // prologue: edge `row` (indices uniform -> scalar loads)
    int sC = csr_src[row];
    int eC = csr_eid[row];
    float xls0 = xl[(size_t)sC * 128 + c0];
    float xls1 = xl[(size_t)sC * 128 + c1];

    for (int i = row; i < rend; ++i) {
        // prefetch next edge's src + xl gather (uniform condition)
        int eN = eC;
        float nx0, nx1;
        bool have = (i + 1 < rend);
        if (have) {
            int sN = csr_src[i + 1];
            eN = csr_eid[i + 1];
            nx0 = xl[(size_t)sN * 128 + c0];
            nx1 = xl[(size_t)sN * 128 + c1];
        }

        // attr: wave-uniform pointer -> scalar dwordx4 loads
        const float4* ap = (const float4*)((eC < N_EDGES)
                              ? ea + (size_t)eC * EDGE_DIM
                              : lattr + (size_t)(eC - N_EDGES) * EDGE_DIM);
        float ax[EDGE_DIM];
        *(float4*)&ax[0]  = ap[0];
        *(float4*)&ax[4]  = ap[1];
        *(float4*)&ax[8]  = ap[2];
        *(float4*)&ax[12] = ap[3];

        float e0 = 0.0f, e1 = 0.0f;
#pragma unroll
        for (int k = 0; k < EDGE_DIM; ++k) {
            e0 = fmaf(ax[k], we0[k], e0);
            e1 = fmaf(ax[k], we1[k], e1);
        }
        float v0 = xls0 + xr0 + e0, v1 = xls1 + xr1 + e1;
        v0 = (v0 > 0.0f) ? v0 : NEG_SLOPE * v0;
        v1 = (v1 > 0.0f) ? v1 : NEG_SLOPE * v1;
        float p0 = red32(v0 * att0);
        float p1 = red32(v1 * att1);

        // defer-max online softmax (THR=8)
        if (p0 - m0 > 8.0f) { float r = __expf(m0 - p0); d0 *= r; acc0 *= r; m0 = p0; }
        float w0 = __expf(p0 - m0); d0 += w0; acc0 += w0 * xls0;
        if (p1 - m1 > 8.0f) { float r = __expf(m1 - p1); d1 *= r; acc1 *= r; m1 = p1; }
        float w1 = __expf(p1 - m1); d1 += w1; acc1 += w1 * xls1;

        if (have) { eC = eN; xls0 = nx0; xls1 = nx1; }
    }

    float o0 = acc0 / d0 + bias[c0];
    float o1 = acc1 / d1 + bias[c1];
    if (DO_ELU) {
        o0 = (o0 > 0.0f) ? o0 : (__expf(o0) - 1.0f);
        o1 = (o1 > 0.0f) ? o1 : (__expf(o1) - 1.0f);
    }
    y[(size_t)node * 128 + c0] = o0;
    y[(size_t)node * 128 + c1] = o1;
}

// ---------------- pool (segmented reduction over sorted batch) + head ----------------
__global__ __launch_bounds__(256) void pool_csr(const float* __restrict__ y,
                                                const int* __restrict__ batch,
                                                float* __restrict__ gsum,
                                                float* __restrict__ gcnt) {
    int base = blockIdx.x * 256;
    int t = threadIdx.x;
    int c = t & 127, h = t >> 7;
    int n = base + h;
    int end = min(base + 256, N_NODES);
    if (n >= end) return;
    float acc = 0.0f, cnt = 0.0f;
    int curb = batch[n];
    for (; n < end; n += 2) {
        int b = batch[n];
        if (b != curb) {
            atomicAdd(&gsum[curb * 128 + c], acc);
            if (c == 0) atomicAdd(&gcnt[curb], cnt);
            acc = 0.0f; cnt = 0.0f; curb = b;
        }
        acc += y[(long long)n * 128 + c];
        cnt += 1.0f;
    }
    atomicAdd(&gsum[curb * 128 + c], acc);
    if (c == 0) atomicAdd(&gcnt[curb], cnt);
}

__global__ __launch_bounds__(128) void head_kernel(
    const float* __restrict__ gsum, const float* __restrict__ gcnt,
    const float* __restrict__ Wg1, const float* __restrict__ bg1,
    const float* __restrict__ Wg2, const float* __restrict__ bg2,
    const float* __restrict__ Wp, const float* __restrict__ bp,
    float* __restrict__ out)
{
    int b = blockIdx.x;
    int j = threadIdx.x;
    __shared__ float g[128], h[128];
    float cntv = fmaxf(gcnt[b], 1.0f);
    g[j] = gsum[b * 128 + j] / cntv;
    __syncthreads();
    float a = bg1[j];
    for (int k = 0; k < 128; ++k) a += g[k] * Wg1[j * 128 + k];
    h[j] = fmaxf(a, 0.0f);
    __syncthreads();
    if (j < 15) {
        float o = bg2[j];
        for (int k = 0; k < 128; ++k) o += h[k] * Wg2[j * 128 + k];
        out[b * 25 + j] = o;
    }
    if (j >= 64 && j < 74) {
        int p = j - 64;
        float o = bp[p];
        for (int k = 0; k < 128; ++k) o += g[k] * Wp[p * 128 + k];
        out[b * 25 + 15 + p] = o;
    }
}

// ---------------- launch ----------------
extern "C" void kernel_launch(void* const* d_in, const int* in_sizes, int n_in,
                              void* d_out, int out_size, void* d_ws, size_t ws_size,
                              hipStream_t stream)
{
    const float* x     = (const float*)d_in[0];
    const int*   ei    = (const int*)  d_in[1];
    const float* ea    = (const float*)d_in[2];
    const int*   batch = (const int*)  d_in[3];
    const float* W1l = (const float*)d_in[4],  *b1l  = (const float*)d_in[5];
    const float* W1r = (const float*)d_in[6],  *b1r  = (const float*)d_in[7];
    const float* W1e = (const float*)d_in[8],  *att1 = (const float*)d_in[9];
    const float* bias1 = (const float*)d_in[10];
    const float* W2l = (const float*)d_in[11], *b2l  = (const float*)d_in[12];
    const float* W2r = (const float*)d_in[13], *b2r  = (const float*)d_in[14];
    const float* W2e = (const float*)d_in[15], *att2 = (const float*)d_in[16];
    const float* bias2 = (const float*)d_in[17];
    const float* Wg1 = (const float*)d_in[18], *bg1 = (const float*)d_in[19];
    const float* Wg2 = (const float*)d_in[20], *bg2 = (const float*)d_in[21];
    const float* Wp  = (const float*)d_in[22], *bp  = (const float*)d_in[23];
    const int* src = ei;
    const int* dst = ei + N_EDGES;

    // workspace layout (float units)
    float* ws = (float*)d_ws;
    size_t o = 0;
    float* xl    = ws + o; o += (size_t)N_NODES * 128;
    float* xr    = ws + o; o += (size_t)N_NODES * 128;
    float* y     = ws + o; o += (size_t)N_NODES * 128;
    float* lattr = ws + o; o += (size_t)N_NODES * EDGE_DIM;
    int* csr_src = (int*)(ws + o); o += (size_t)EN_TOT;
    int* csr_eid = (int*)(ws + o); o += (size_t)EN_TOT;
    int* offs    = (int*)(ws + o); o += (size_t)N_NODES + 1;
    int* deg     = (int*)(ws + o); o += (size_t)N_NODES;          // start of zero region
    int* cursor  = (int*)(ws + o); o += (size_t)N_NODES;
    float* gsum  = ws + o; o += (size_t)BATCH * 128;
    float* gcnt  = ws + o; o += (size_t)BATCH;                     // end of zero region
    int* bsum    = (int*)(ws + o); o += 512;
    int* incl    = (int*)y;  // scan temp, dead before y is written

    float* out = (float*)d_out;

    // zero deg, cursor, gsum, gcnt (contiguous)
    long long nz = (long long)N_NODES * 2 + BATCH * 128 + BATCH;
    zero_kernel<<<512, 256, 0, stream>>>((float*)deg, nz);

    // ---- CSR build (shared by both layers) ----
    count_deg<<<(N_EDGES + 255) / 256, 256, 0, stream>>>(dst, deg);
    scan1<<<NB_SCAN, 256, 0, stream>>>(deg, incl, bsum);
    scan2<<<1, 512, 0, stream>>>(bsum);
    scan3<<<NB_SCAN, 256, 0, stream>>>(incl, deg, bsum, offs);
    scatter<<<(EN_TOT + 255) / 256, 256, 0, stream>>>(src, dst, offs, cursor, csr_src, csr_eid);
    loopattr_csr<<<(N_NODES + 3) / 4, 256, 0, stream>>>(offs, csr_eid, ea, lattr);

    const int GAT_BLK = (N_NODES + 3) / 4;

    // ---- layer 1 ----
    dual_linear<32><<<(N_NODES + 31) / 32, 256, 0, stream>>>(x, W1l, b1l, W1r, b1r, xl, xr, N_NODES);
    gat_fused<1><<<GAT_BLK, 256, 0, stream>>>(offs, csr_src, csr_eid, ea, lattr,
                                              W1e, att1, xl, xr, bias1, y);

    // ---- layer 2 ----
    dual_linear<128><<<(N_NODES + 31) / 32, 256, 0, stream>>>(y, W2l, b2l, W2r, b2r, xl, xr, N_NODES);
    gat_fused<0><<<GAT_BLK, 256, 0, stream>>>(offs, csr_src, csr_eid, ea, lattr,
                                              W2e, att2, xl, xr, bias2, y);

    // ---- pool + head ----
    pool_csr<<<(N_NODES + 255) / 256, 256, 0, stream>>>(y, batch, gsum, gcnt);
    head_kernel<<<BATCH, 128, 0, stream>>>(gsum, gcnt, Wg1, bg1, Wg2, bg2, Wp, bp, out);
}